// Round 8
// baseline (49.113 us; speedup 1.0000x reference)
//
#include <hip/hip_runtime.h>
#include <cmath>

// Cox partial likelihood (Breslow) loss, N=16384.
// denom[i] = sum_j [t_j >= t_i] * exp(est_j)
// loss = sum_i ev_i * (log(denom[i]) - est[i]) / max(sum ev, 1)
//
// R8: 2 kernels. K1 rank-sorts 64 chunks of 256 (float keys + index
// tiebreak -> unique ranks, deterministic) and suffix-sums exp(est);
// also zero-inits the K2 reduction cells (kernel-boundary visibility).
// K2 searches + reduces + finalizes via INTEGER atomics (deterministic,
// no __threadfence -- R5 lesson: L2 writeback fences cost >>100us).

#define CS     256                  // chunk size (= K1 block size)
#define NCH    64                   // number of chunks (n / CS)
#define SUBS   16                   // sub-threads per i in K2
#define CPS    (NCH / SUBS)         // 4 chunks per sub-thread
#define K2THR  512                  // K2 block: 32 i's per block
#define K2NB   512                  // K2 grid (n / 32)
#define QSCALE 1099511627776.0      // 2^40 fixed-point scale

// ---------------------------------------------------------------------------
// K1: per-chunk rank sort + suffix sums of e = exp(est).
__global__ __launch_bounds__(CS)
void cox_sort(const float2* __restrict__ tg,
              const float* __restrict__ est,
              float* __restrict__ ts,    // [NCH*CS] sorted t
              float* __restrict__ ss,    // [NCH*CS] suffix sums of e
              unsigned long long* __restrict__ lacc,
              unsigned long long* __restrict__ vacc,
              int* __restrict__ cnt) {
    __shared__ float st[CS];
    __shared__ float srt[CS], sre[CS];

    const int tid = threadIdx.x;
    const int j   = blockIdx.x * CS + tid;

    if (blockIdx.x == 0 && tid == 0) { *lacc = 0ull; *vacc = 0ull; *cnt = 0; }

    const float tj = tg[j].x;
    const float ej = expf(est[j]);
    st[tid] = tj;
    __syncthreads();

    // rank = #{k : (t_k, k) < (t_j, j)}  -- unique -> permutation
    int rank = 0;
    const float4* t4 = (const float4*)st;
    #pragma unroll 8
    for (int k4 = 0; k4 < CS / 4; ++k4) {
        float4 p = t4[k4];
        const int k = k4 * 4;
        rank += (p.x < tj) || (p.x == tj && (k + 0) < tid);
        rank += (p.y < tj) || (p.y == tj && (k + 1) < tid);
        rank += (p.z < tj) || (p.z == tj && (k + 2) < tid);
        rank += (p.w < tj) || (p.w == tj && (k + 3) < tid);
    }
    srt[rank] = tj;
    sre[rank] = ej;
    __syncthreads();

    // inclusive suffix scan of sre (fixed order -> deterministic)
    #pragma unroll
    for (int off = 1; off < CS; off <<= 1) {
        float add = (tid + off < CS) ? sre[tid + off] : 0.f;
        __syncthreads();
        sre[tid] += add;
        __syncthreads();
    }

    ts[j] = srt[tid];
    ss[j] = sre[tid];
}

// ---------------------------------------------------------------------------
// K2: per-i denom via NCH branchless lower_bounds, contribution, block
// reduce, then device-wide reduce via int64 fixed-point atomics. The last
// arriving block (atomic counter) computes and writes the final scalar.
__global__ __launch_bounds__(K2THR)
void cox_search(const float2* __restrict__ tg,
                const float* __restrict__ est,
                const float* __restrict__ ts,
                const float* __restrict__ ss,
                unsigned long long* __restrict__ lacc,
                unsigned long long* __restrict__ vacc,
                int* __restrict__ cnt,
                float* __restrict__ out) {
    __shared__ float sl[K2THR / 64], sv[K2THR / 64];

    const int tid = threadIdx.x;
    const int sub = tid & (SUBS - 1);
    const int i   = blockIdx.x * (K2THR / SUBS) + (tid >> 4);

    const float ti = tg[i].x;

    float d = 0.f;
    #pragma unroll
    for (int cc = 0; cc < CPS; ++cc) {
        const int c = sub * CPS + cc;
        const float* tsc = ts + (c << 8);
        // branchless lower_bound: pos = #{k : tsc[k] < ti}, pos in [0,256]
        int pos = 0;
        #pragma unroll
        for (int s = CS / 2; s >= 1; s >>= 1)
            pos += (tsc[pos + s - 1] < ti) ? s : 0;
        pos += (tsc[pos] < ti) ? 1 : 0;
        d += (pos < CS) ? ss[(c << 8) + pos] : 0.f;   // sum over t >= ti
    }

    // combine the 16 subs (fixed tree -> deterministic)
    d += __shfl_down(d, 8, 16);
    d += __shfl_down(d, 4, 16);
    d += __shfl_down(d, 2, 16);
    d += __shfl_down(d, 1, 16);

    float contrib = 0.f, ev = 0.f;
    if (sub == 0) {
        ev      = (tg[i].y != 0.f) ? 1.f : 0.f;
        contrib = ev * (logf(d) - est[i]);
    }
    #pragma unroll
    for (int off = 32; off > 0; off >>= 1) {
        contrib += __shfl_down(contrib, off, 64);
        ev      += __shfl_down(ev, off, 64);
    }
    if ((tid & 63) == 0) { sl[tid >> 6] = contrib; sv[tid >> 6] = ev; }
    __syncthreads();

    if (tid == 0) {
        float l = 0.f, v = 0.f;
        #pragma unroll
        for (int w = 0; w < K2THR / 64; ++w) { l += sl[w]; v += sv[w]; }

        // quantize (exact int adds -> deterministic device-wide sum)
        long long ql = (long long)rint((double)l * QSCALE);
        long long qv = (long long)rint((double)v);   // integer event count
        atomicAdd(lacc, (unsigned long long)ql);
        atomicAdd(vacc, (unsigned long long)qv);
        // ensure payload atomics reached the coherence point BEFORE the
        // arrival counter increments (no threadfence needed)
        asm volatile("s_waitcnt vmcnt(0)" ::: "memory");
        int arr = atomicAdd(cnt, 1);
        if (arr == K2NB - 1) {
            // true last arriver: all payload adds are complete
            unsigned long long Lq = atomicAdd(lacc, 0ull);
            unsigned long long Vq = atomicAdd(vacc, 0ull);
            double L = (double)(long long)Lq / QSCALE;
            double V = (double)(long long)Vq;
            out[0] = (float)(L / fmax(V, 1.0));
        }
    }
}

// ---------------------------------------------------------------------------
extern "C" void kernel_launch(void* const* d_in, const int* in_sizes, int n_in,
                              void* d_out, int out_size, void* d_ws, size_t ws_size,
                              hipStream_t stream) {
    const float*  est = (const float*)d_in[0];
    const float2* tg  = (const float2*)d_in[1];   // target[N][2] = (t, event)
    float*        out = (float*)d_out;

    const int n = in_sizes[0];                    // 16384

    float* ws = (float*)d_ws;
    float* ts = ws;                               // [n]
    float* ss = ws + n;                           // [n]
    unsigned long long* lacc = (unsigned long long*)(ws + 2 * n);
    unsigned long long* vacc = lacc + 1;
    int*                cnt  = (int*)(vacc + 1);

    cox_sort<<<n / CS, CS, 0, stream>>>(tg, est, ts, ss, lacc, vacc, cnt);
    cox_search<<<K2NB, K2THR, 0, stream>>>(tg, est, ts, ss, lacc, vacc, cnt, out);
}

// Round 9
// 28.036 us; speedup vs baseline: 1.7518x; 1.7518x over previous
//
#include <hip/hip_runtime.h>
#include <cmath>

// Cox partial likelihood (Breslow) loss, N=16384.
// denom[i] = sum_j [t_j >= t_i] * exp(est_j)
// loss = sum_i ev_i * (log(denom[i]) - est[i]) / max(sum ev, 1)
//
// R9: O(N log N), wave-coherent searches. K1 rank-sorts 512-elem chunks
// (unique u64 keys -> deterministic) + suffix-sums exp(est) + carries the
// permutation. K2 processes queries IN SORTED ORDER so a wave's 16 queries
// probe ~adjacent table positions (1-2 cache lines/probe instead of ~64).
// K3 finalizes. No device fences, no float atomics (R5/R8 lessons).

#define CSZ   512                 // chunk size (= K1 block size)
#define NCH   32                  // chunks (n / CSZ)
#define SUBS  4                   // sub-threads per query in K2
#define CHPS  (NCH / SUBS)        // 8 chunks per sub-thread
#define QPB   64                  // queries per K2 block
#define K2THR (QPB * SUBS)        // 256 threads
#define K2NB  256                 // n / QPB

// ---------------------------------------------------------------------------
// K1: per-chunk rank sort + suffix sums of e = exp(est) + orig-index perm.
__global__ __launch_bounds__(CSZ)
void cox_sort(const float2* __restrict__ tg,
              const float* __restrict__ est,
              float* __restrict__ ts,    // [n] sorted t (per chunk)
              float* __restrict__ ss,    // [n] suffix sums of e (per chunk)
              int* __restrict__ so) {    // [n] orig index of sorted elem
    __shared__ unsigned long long skey[CSZ];  // 4 KB
    __shared__ float sst[CSZ], sse[CSZ];      // 4 KB
    __shared__ int   sso[CSZ];                // 2 KB

    const int tid = threadIdx.x;
    const int j   = blockIdx.x * CSZ + tid;

    const float tj = tg[j].x;
    const float ej = expf(est[j]);
    const unsigned long long key =
        ((unsigned long long)__float_as_uint(tj) << 32) | (unsigned)tid;
    skey[tid] = key;
    __syncthreads();

    // rank = #{k : key_k < key}  (keys unique -> rank is a permutation)
    int rank = 0;
    const ulonglong2* k2 = (const ulonglong2*)skey;
    #pragma unroll 8
    for (int k = 0; k < CSZ / 2; ++k) {
        ulonglong2 p = k2[k];
        rank += (p.x < key) ? 1 : 0;
        rank += (p.y < key) ? 1 : 0;
    }

    sst[rank] = tj;
    sse[rank] = ej;
    sso[rank] = j;
    __syncthreads();

    // inclusive suffix scan of sse (fixed order -> deterministic)
    #pragma unroll
    for (int off = 1; off < CSZ; off <<= 1) {
        float add = (tid + off < CSZ) ? sse[tid + off] : 0.f;
        __syncthreads();
        sse[tid] += add;
        __syncthreads();
    }

    ts[j] = sst[tid];
    ss[j] = sse[tid];
    so[j] = sso[tid];
}

// ---------------------------------------------------------------------------
// K2: queries processed in per-chunk sorted order -> wave-coherent probes.
// Block = 256 thr = 64 queries x 4 subs; sub s searches chunks s*8..s*8+7.
__global__ __launch_bounds__(K2THR)
void cox_search(const float2* __restrict__ tg,
                const float* __restrict__ est,
                const float* __restrict__ ts,
                const float* __restrict__ ss,
                const int* __restrict__ so,
                float* __restrict__ ploss,
                float* __restrict__ pev) {
    __shared__ float sl[K2THR / 64], sv[K2THR / 64];

    const int tid = threadIdx.x;
    const int sub = tid & (SUBS - 1);
    const int qid = blockIdx.x * QPB + (tid >> 2);  // sorted position

    const float ti = ts[qid];    // coalesced: 4 lanes share, 16 vals/wave

    float d = 0.f;
    #pragma unroll
    for (int cc = 0; cc < CHPS; ++cc) {
        const int c = sub * CHPS + cc;
        const float* tsc = ts + (c << 9);
        // branchless lower_bound: pos = #{k : tsc[k] < ti}, pos in [0,512]
        int pos = 0;
        #pragma unroll
        for (int s = 256; s >= 1; s >>= 1)
            pos += (tsc[pos + s - 1] < ti) ? s : 0;
        pos += (tsc[pos] < ti) ? 1 : 0;
        d += (pos < CSZ) ? ss[(c << 9) + pos] : 0.f;  // sum over t >= ti
    }

    // combine 4 subs (fixed tree -> deterministic)
    d += __shfl_down(d, 2, 4);
    d += __shfl_down(d, 1, 4);

    float contrib = 0.f, ev = 0.f;
    if (sub == 0) {
        const int io = so[qid];
        ev      = (tg[io].y != 0.f) ? 1.f : 0.f;
        contrib = ev * (logf(d) - est[io]);
    }
    // reduce over lanes ==0 mod 4 within the wave (others hold 0)
    #pragma unroll
    for (int off = 32; off >= 4; off >>= 1) {
        contrib += __shfl_down(contrib, off, 64);
        ev      += __shfl_down(ev, off, 64);
    }
    if ((tid & 63) == 0) { sl[tid >> 6] = contrib; sv[tid >> 6] = ev; }
    __syncthreads();
    if (tid == 0) {
        float l = 0.f, v = 0.f;
        #pragma unroll
        for (int w = 0; w < K2THR / 64; ++w) { l += sl[w]; v += sv[w]; }
        ploss[blockIdx.x] = l;
        pev[blockIdx.x]   = v;
    }
}

// ---------------------------------------------------------------------------
// K3: final reduction of block partials -> scalar loss.
__global__ void cox_finalize(const float* __restrict__ ploss,
                             const float* __restrict__ pev,
                             float* __restrict__ out,
                             int nblocks) {
    const int tid = threadIdx.x;  // one wave
    float l = 0.f, v = 0.f;
    for (int k = tid; k < nblocks; k += 64) {
        l += ploss[k];
        v += pev[k];
    }
    #pragma unroll
    for (int off = 32; off > 0; off >>= 1) {
        l += __shfl_down(l, off, 64);
        v += __shfl_down(v, off, 64);
    }
    if (tid == 0) out[0] = l / fmaxf(v, 1.f);
}

// ---------------------------------------------------------------------------
extern "C" void kernel_launch(void* const* d_in, const int* in_sizes, int n_in,
                              void* d_out, int out_size, void* d_ws, size_t ws_size,
                              hipStream_t stream) {
    const float*  est = (const float*)d_in[0];
    const float2* tg  = (const float2*)d_in[1];   // target[N][2] = (t, event)
    float*        out = (float*)d_out;

    const int n = in_sizes[0];                    // 16384

    float* ws    = (float*)d_ws;
    float* ts    = ws;                            // [n]
    float* ss    = ws + n;                        // [n]
    int*   so    = (int*)(ws + 2 * n);            // [n]
    float* ploss = ws + 3 * n;                    // [K2NB]
    float* pev   = ploss + K2NB;                  // [K2NB]

    cox_sort<<<n / CSZ, CSZ, 0, stream>>>(tg, est, ts, ss, so);
    cox_search<<<K2NB, K2THR, 0, stream>>>(tg, est, ts, ss, so, ploss, pev);
    cox_finalize<<<1, 64, 0, stream>>>(ploss, pev, out, K2NB);
}

// Round 10
// 20.290 us; speedup vs baseline: 2.4205x; 1.3818x over previous
//
#include <hip/hip_runtime.h>
#include <cmath>

// Cox partial likelihood (Breslow) loss, N=16384.
// denom[i] = sum_j [t_j >= t_i] * exp(est_j)
// loss = sum_i ev_i * (log(denom[i]) - est[i]) / max(sum ev, 1)
//
// R10: O(N log N). K1: chunk rank-sort + suffix sums + permutation.
// K2: stages the FULL sorted-t table (64KB) in LDS and runs the 8
// per-chunk binary searches ROUND-INTERLEAVED (8 independent ds_reads in
// flight per round -> latency-hidden), ss gathered from L2. K3: finalize.
// Deterministic: unique sort keys, fixed reduction trees, no float atomics,
// no device fences (R5/R8 lessons).

#define CSZ   512                 // chunk size (= K1 block size)
#define NCH   32                  // chunks (n / CSZ)
#define SUBS  4                   // sub-threads per query in K2
#define CHPS  (NCH / SUBS)        // 8 chunks per sub-thread
#define QPB   64                  // queries per K2 block
#define K2THR (QPB * SUBS)        // 256 threads
#define K2NB  256                 // n / QPB

// ---------------------------------------------------------------------------
// K1: per-chunk rank sort + suffix sums of e = exp(est) + orig-index perm.
__global__ __launch_bounds__(CSZ)
void cox_sort(const float2* __restrict__ tg,
              const float* __restrict__ est,
              float* __restrict__ ts,    // [n] sorted t (per chunk)
              float* __restrict__ ss,    // [n] suffix sums of e (per chunk)
              int* __restrict__ so) {    // [n] orig index of sorted elem
    __shared__ unsigned long long skey[CSZ];   // 4 KB
    __shared__ float sst[CSZ];                 // 2 KB
    __shared__ float sea[CSZ], seb[CSZ];       // 4 KB (ping-pong scan)
    __shared__ int   sso[CSZ];                 // 2 KB

    const int tid = threadIdx.x;
    const int j   = blockIdx.x * CSZ + tid;

    const float tj = tg[j].x;
    const float ej = expf(est[j]);
    const unsigned long long key =
        ((unsigned long long)__float_as_uint(tj) << 32) | (unsigned)tid;
    skey[tid] = key;
    __syncthreads();

    // rank = #{k : key_k < key}  (keys unique -> rank is a permutation)
    int rank = 0;
    const ulonglong2* k2 = (const ulonglong2*)skey;
    #pragma unroll 8
    for (int k = 0; k < CSZ / 2; ++k) {
        ulonglong2 p = k2[k];
        rank += (p.x < key) ? 1 : 0;
        rank += (p.y < key) ? 1 : 0;
    }

    sst[rank] = tj;
    sea[rank] = ej;
    sso[rank] = j;
    __syncthreads();

    // inclusive suffix scan, ping-pong (1 barrier per round, deterministic)
    float* a = sea;
    float* b = seb;
    #pragma unroll
    for (int off = 1; off < CSZ; off <<= 1) {
        b[tid] = a[tid] + ((tid + off < CSZ) ? a[tid + off] : 0.f);
        __syncthreads();
        float* tmp = a; a = b; b = tmp;
    }

    ts[j] = sst[tid];
    ss[j] = a[tid];
    so[j] = sso[tid];
}

// ---------------------------------------------------------------------------
// K2: full sorted-t table in LDS; 8 chunk-searches per sub, round-
// interleaved for ILP. Block = 256 thr = 64 queries x 4 subs.
__global__ __launch_bounds__(K2THR)
void cox_search(const float2* __restrict__ tg,
                const float* __restrict__ est,
                const float* __restrict__ ts,
                const float* __restrict__ ss,
                const int* __restrict__ so,
                float* __restrict__ ploss,
                float* __restrict__ pev) {
    __shared__ float lts[NCH * CSZ];            // 64 KB: whole sorted table
    __shared__ float sl[K2THR / 64], sv[K2THR / 64];

    const int tid = threadIdx.x;
    const int sub = tid & (SUBS - 1);
    const int qid = blockIdx.x * QPB + (tid >> 2);  // per-chunk sorted pos

    // ---- stage the full table (L2-resident source, coalesced float4) ----
    {
        float4* l4 = (float4*)lts;
        const float4* g4 = (const float4*)ts;
        #pragma unroll
        for (int k = 0; k < (NCH * CSZ / 4) / K2THR; ++k)
            l4[tid + k * K2THR] = g4[tid + k * K2THR];
    }
    __syncthreads();

    const float ti = lts[qid];

    // ---- 8 branchless lower_bounds, round-interleaved (8-wide ILP) ----
    int pos[CHPS];
    #pragma unroll
    for (int c = 0; c < CHPS; ++c) pos[c] = 0;

    #pragma unroll
    for (int s = CSZ / 2; s >= 1; s >>= 1) {
        float v[CHPS];
        #pragma unroll
        for (int c = 0; c < CHPS; ++c)
            v[c] = lts[((sub * CHPS + c) << 9) + pos[c] + s - 1];
        #pragma unroll
        for (int c = 0; c < CHPS; ++c)
            pos[c] += (v[c] < ti) ? s : 0;
    }
    {   // final refinement round: pos in [0,512]
        float v[CHPS];
        #pragma unroll
        for (int c = 0; c < CHPS; ++c)
            v[c] = lts[((sub * CHPS + c) << 9) + pos[c]];
        #pragma unroll
        for (int c = 0; c < CHPS; ++c)
            pos[c] += (v[c] < ti) ? 1 : 0;
    }

    // ---- gather suffix values (8 independent L2 loads) ----
    float d = 0.f;
    #pragma unroll
    for (int c = 0; c < CHPS; ++c)
        d += (pos[c] < CSZ) ? ss[((sub * CHPS + c) << 9) + pos[c]] : 0.f;

    // combine 4 subs (fixed tree -> deterministic)
    d += __shfl_down(d, 2, 4);
    d += __shfl_down(d, 1, 4);

    float contrib = 0.f, ev = 0.f;
    if (sub == 0) {
        const int io = so[qid];
        ev      = (tg[io].y != 0.f) ? 1.f : 0.f;
        contrib = ev * (logf(d) - est[io]);
    }
    #pragma unroll
    for (int off = 32; off >= 4; off >>= 1) {
        contrib += __shfl_down(contrib, off, 64);
        ev      += __shfl_down(ev, off, 64);
    }
    if ((tid & 63) == 0) { sl[tid >> 6] = contrib; sv[tid >> 6] = ev; }
    __syncthreads();
    if (tid == 0) {
        float l = 0.f, v = 0.f;
        #pragma unroll
        for (int w = 0; w < K2THR / 64; ++w) { l += sl[w]; v += sv[w]; }
        ploss[blockIdx.x] = l;
        pev[blockIdx.x]   = v;
    }
}

// ---------------------------------------------------------------------------
// K3: final reduction of block partials -> scalar loss.
__global__ void cox_finalize(const float* __restrict__ ploss,
                             const float* __restrict__ pev,
                             float* __restrict__ out,
                             int nblocks) {
    const int tid = threadIdx.x;  // one wave
    float l = 0.f, v = 0.f;
    for (int k = tid; k < nblocks; k += 64) {
        l += ploss[k];
        v += pev[k];
    }
    #pragma unroll
    for (int off = 32; off > 0; off >>= 1) {
        l += __shfl_down(l, off, 64);
        v += __shfl_down(v, off, 64);
    }
    if (tid == 0) out[0] = l / fmaxf(v, 1.f);
}

// ---------------------------------------------------------------------------
extern "C" void kernel_launch(void* const* d_in, const int* in_sizes, int n_in,
                              void* d_out, int out_size, void* d_ws, size_t ws_size,
                              hipStream_t stream) {
    const float*  est = (const float*)d_in[0];
    const float2* tg  = (const float2*)d_in[1];   // target[N][2] = (t, event)
    float*        out = (float*)d_out;

    const int n = in_sizes[0];                    // 16384

    float* ws    = (float*)d_ws;
    float* ts    = ws;                            // [n]
    float* ss    = ws + n;                        // [n]
    int*   so    = (int*)(ws + 2 * n);            // [n]
    float* ploss = ws + 3 * n;                    // [K2NB]
    float* pev   = ploss + K2NB;                  // [K2NB]

    cox_sort<<<n / CSZ, CSZ, 0, stream>>>(tg, est, ts, ss, so);
    cox_search<<<K2NB, K2THR, 0, stream>>>(tg, est, ts, ss, so, ploss, pev);
    cox_finalize<<<1, 64, 0, stream>>>(ploss, pev, out, K2NB);
}